// Round 1
// baseline (571.619 us; speedup 1.0000x reference)
//
#include <hip/hip_runtime.h>
#include <hip/hip_bf16.h>

#define B_ 32
#define C_ 512
#define N_ 4096
#define T_ 72
#define K_ 64
#define KP 80            // clusters padded to 5 MFMA m-tiles
#define EPSF 1e-12f

typedef unsigned short u16;
typedef unsigned int u32;
typedef __attribute__((ext_vector_type(8))) short bf16x8;
typedef __attribute__((ext_vector_type(4))) float f32x4;

__device__ __forceinline__ u16 f2bf(float v) {
    __hip_bfloat16 h = __float2bfloat16(v);   // RNE
    return *reinterpret_cast<u16*>(&h);
}

// ---------------------------------------------------------------------------
// Prep: W padded [80][512] -> bf16 (rows >=72 zero); bias padded (-1e30 pads
// so padded rows vanish in softmax).
// ---------------------------------------------------------------------------
__global__ __launch_bounds__(256) void k_prep(
    const float* __restrict__ conv_w, const float* __restrict__ conv_b,
    u16* __restrict__ Wp, float* __restrict__ bp)
{
    const int idx = blockIdx.x * 256 + threadIdx.x;
    if (idx < KP * C_) {
        const int k = idx >> 9, c = idx & (C_ - 1);
        Wp[idx] = f2bf(k < T_ ? conv_w[k * C_ + c] : 0.f);
    } else if (idx < KP * C_ + KP) {
        const int j = idx - KP * C_;
        bp[j] = (j < T_) ? conv_b[j] : -1e30f;
    }
}

// ---------------------------------------------------------------------------
// Assign (wave-independent, barrier-free): each wave owns 16 n-rows, stages
// them quarter-by-quarter (128 c) into PRIVATE LDS.  Next quarter's global
// loads are issued before the MFMA phase (latency hides under MFMA+consume).
// c-pair float4 loads -> packed u32 LDS writes (2 lanes/bank = free).
// Channel sumsq + inv-norm kept fully in registers via stride-4 shfl reduce.
// LDS 17.4 KB/block.  No __syncthreads anywhere.
// ---------------------------------------------------------------------------
#define AN 64
__global__ __launch_bounds__(256) void k_assign(
    const float* __restrict__ x, const u16* __restrict__ Wp,
    const float* __restrict__ bp, u16* __restrict__ assignp,
    float* __restrict__ mass)
{
    __shared__ u16 xw[4][16][136];   // per-wave 16n x 128c bf16; pitch 136 u16
                                     // (row stride 272B: ds_read_b128 pattern
                                     //  lands 2 lanes/4-bank granule = free)

    const int t  = threadIdx.x;
    const int b  = blockIdx.y;
    const int n0 = blockIdx.x * AN;

    const int lane = t & 63, w = t >> 6;
    const int q  = lane >> 4, nl = lane & 15;   // MFMA roles
    const int nq = lane & 3,  cg = lane >> 2;   // staging roles

    // wave-private n-base: this wave stages ONLY its own 16 n
    const float* xb = x + (size_t)b * C_ * N_ + n0 + 16 * w + 4 * nq;

    f32x4 acc[5];
    #pragma unroll
    for (int mt = 0; mt < 5; ++mt) acc[mt] = (f32x4)0.f;
    float ss[4] = {0.f, 0.f, 0.f, 0.f};

    // prologue: issue quarter-0 loads (8 x float4 in flight per thread)
    float4 va[4], vc[4];
    #pragma unroll
    for (int ci = 0; ci < 4; ++ci) {
        const size_t coff = (size_t)(32 * ci + 2 * cg) * N_;
        va[ci] = *(const float4*)(xb + coff);
        vc[ci] = *(const float4*)(xb + coff + N_);
    }

    #pragma unroll
    for (int qtr = 0; qtr < 4; ++qtr) {
        // ---- consume regs -> sumsq + LDS (packed u32 writes) ----
        #pragma unroll
        for (int ci = 0; ci < 4; ++ci) {
            const int cl = 32 * ci + 2 * cg;
            const float4 v0 = va[ci], v1 = vc[ci];
            ss[0] = fmaf(v0.x, v0.x, ss[0]); ss[0] = fmaf(v1.x, v1.x, ss[0]);
            ss[1] = fmaf(v0.y, v0.y, ss[1]); ss[1] = fmaf(v1.y, v1.y, ss[1]);
            ss[2] = fmaf(v0.z, v0.z, ss[2]); ss[2] = fmaf(v1.z, v1.z, ss[2]);
            ss[3] = fmaf(v0.w, v0.w, ss[3]); ss[3] = fmaf(v1.w, v1.w, ss[3]);
            *(u32*)&xw[w][4 * nq + 0][cl] = (u32)f2bf(v0.x) | ((u32)f2bf(v1.x) << 16);
            *(u32*)&xw[w][4 * nq + 1][cl] = (u32)f2bf(v0.y) | ((u32)f2bf(v1.y) << 16);
            *(u32*)&xw[w][4 * nq + 2][cl] = (u32)f2bf(v0.z) | ((u32)f2bf(v1.z) << 16);
            *(u32*)&xw[w][4 * nq + 3][cl] = (u32)f2bf(v0.w) | ((u32)f2bf(v1.w) << 16);
        }
        // ---- issue next quarter's loads BEFORE MFMA (latency hiding) ----
        if (qtr < 3) {
            #pragma unroll
            for (int ci = 0; ci < 4; ++ci) {
                const size_t coff = (size_t)((qtr + 1) * 128 + 32 * ci + 2 * cg) * N_;
                va[ci] = *(const float4*)(xb + coff);
                vc[ci] = *(const float4*)(xb + coff + N_);
            }
        }
        // ---- MFMA over this quarter (K = 128 in 4 steps of 32) ----
        const u16* wq = Wp + (size_t)nl * C_ + qtr * 128 + q * 8;
        #pragma unroll
        for (int ks = 0; ks < 4; ++ks) {
            const bf16x8 bfr = *(const bf16x8*)&xw[w][nl][ks * 32 + q * 8];
            #pragma unroll
            for (int mt = 0; mt < 5; ++mt) {
                const bf16x8 af = *(const bf16x8*)(wq + (size_t)(mt * 16) * C_ + ks * 32);
                acc[mt] = __builtin_amdgcn_mfma_f32_16x16x32_bf16(af, bfr, acc[mt], 0, 0, 0);
            }
        }
    }

    // ---- inv-norm fully in registers: reduce ss over the 16 lanes that ----
    // ---- share nq (stride-4 lane groups), then shuffle to MFMA layout  ----
    #pragma unroll
    for (int j = 0; j < 4; ++j) {
        ss[j] += __shfl_xor(ss[j], 4, 64);
        ss[j] += __shfl_xor(ss[j], 8, 64);
        ss[j] += __shfl_xor(ss[j], 16, 64);
        ss[j] += __shfl_xor(ss[j], 32, 64);
    }
    float inv[4];
    #pragma unroll
    for (int j = 0; j < 4; ++j) inv[j] = 1.0f / fmaxf(sqrtf(ss[j]), EPSF);

    const int src = nl >> 2;                 // lane 0..3 has nq == nl>>2
    const float i0 = __shfl(inv[0], src, 64);
    const float i1 = __shfl(inv[1], src, 64);
    const float i2 = __shfl(inv[2], src, 64);
    const float i3 = __shfl(inv[3], src, 64);
    const float invn = (nl & 2) ? ((nl & 1) ? i3 : i2) : ((nl & 1) ? i1 : i0);
    const int nglob = n0 + 16 * w + nl;

    // ---- epilogue: softmax in C-layout regs (unchanged math) ----
    float lg[5][4];
    #pragma unroll
    for (int mt = 0; mt < 5; ++mt)
        #pragma unroll
        for (int r = 0; r < 4; ++r)
            lg[mt][r] = acc[mt][r] * invn + bp[mt * 16 + q * 4 + r];

    float mx = -1e30f;
    #pragma unroll
    for (int mt = 0; mt < 5; ++mt)
        #pragma unroll
        for (int r = 0; r < 4; ++r) mx = fmaxf(mx, lg[mt][r]);
    mx = fmaxf(mx, __shfl_xor(mx, 16, 64));
    mx = fmaxf(mx, __shfl_xor(mx, 32, 64));

    float s = 0.f;
    #pragma unroll
    for (int mt = 0; mt < 5; ++mt)
        #pragma unroll
        for (int r = 0; r < 4; ++r) {
            lg[mt][r] = __expf(lg[mt][r] - mx);
            s += lg[mt][r];
        }
    s += __shfl_xor(s, 16, 64);
    s += __shfl_xor(s, 32, 64);
    const float rs = 1.0f / s;

    #pragma unroll
    for (int mt = 0; mt < 4; ++mt)          // real clusters only
        #pragma unroll
        for (int r = 0; r < 4; ++r) {
            const float a = lg[mt][r] * rs;
            float msum = a;
            msum += __shfl_xor(msum, 1, 64);
            msum += __shfl_xor(msum, 2, 64);
            msum += __shfl_xor(msum, 4, 64);
            msum += __shfl_xor(msum, 8, 64);
            const int k = mt * 16 + q * 4 + r;
            if (nl == 0) atomicAdd(&mass[b * K_ + k], msum);
            assignp[((size_t)b * K_ + k) * N_ + nglob] = f2bf(a * invn);
        }
}

// ---------------------------------------------------------------------------
// Agg (wave-independent, barrier-free): agg[k][c] = sum_n a'[k,n]*x_bf16[c,n].
// A-fragments read DIRECTLY from global assignp (16 rows x 64B per instr,
// fully-consumed lines, L1/L2-hot) -> no At staging, no barriers.  B (x,
// cvt bf16) staged into wave-private LDS with one-step register prefetch.
// NCH=8 -> 2048 blocks (8/CU).  LDS 9.2 KB/block.
// ---------------------------------------------------------------------------
#define GBK 64
#define NCH 8
__global__ __launch_bounds__(256) void k_agg(
    const float* __restrict__ x, const u16* __restrict__ assignp,
    float* __restrict__ out)
{
    __shared__ u16 Bt[4][16][72];   // per-wave 16c x 64n bf16, pitch 72

    const int t  = threadIdx.x;
    const int b  = blockIdx.z;
    const int nc0 = blockIdx.y * (N_ / NCH);
    const int c0  = blockIdx.x * 64;

    const int lane = t & 63, w = t >> 6;
    const int q = lane >> 4, nl = lane & 15;     // MFMA roles
    const int nq16 = lane & 15, cj = lane >> 4;  // staging roles

    f32x4 acc[4];
    #pragma unroll
    for (int mt = 0; mt < 4; ++mt) acc[mt] = (f32x4)0.f;

    const u16*   ab = assignp + (size_t)b * K_ * N_ + (size_t)nl * N_ + q * 8;
    const float* xb = x + ((size_t)b * C_ + c0 + 16 * w) * N_ + 4 * nq16;

    // prologue: issue first step's B loads
    float4 vb[4];
    #pragma unroll
    for (int p = 0; p < 4; ++p)
        vb[p] = *(const float4*)(xb + (size_t)(4 * p + cj) * N_ + nc0);

    #pragma unroll 1
    for (int n0 = nc0; n0 < nc0 + N_ / NCH; n0 += GBK) {
        // consume regs -> wave-private LDS (ds_write_b64)
        #pragma unroll
        for (int p = 0; p < 4; ++p) {
            const float4 v = vb[p];
            uint2 pk;
            pk.x = (u32)f2bf(v.x) | ((u32)f2bf(v.y) << 16);
            pk.y = (u32)f2bf(v.z) | ((u32)f2bf(v.w) << 16);
            *(uint2*)&Bt[w][4 * p + cj][4 * nq16] = pk;
        }
        // prefetch next step's B (in flight across the MFMA phase)
        if (n0 + GBK < nc0 + N_ / NCH) {
            #pragma unroll
            for (int p = 0; p < 4; ++p)
                vb[p] = *(const float4*)(xb + (size_t)(4 * p + cj) * N_ + n0 + GBK);
        }
        // MFMA: B from private LDS, A direct from global (L1-hot)
        #pragma unroll
        for (int kk = 0; kk < 2; ++kk) {
            const bf16x8 bfr = *(const bf16x8*)&Bt[w][nl][kk * 32 + q * 8];
            #pragma unroll
            for (int mt = 0; mt < 4; ++mt) {
                const bf16x8 af = *(const bf16x8*)(ab + (size_t)(mt * 16) * N_ + n0 + kk * 32);
                acc[mt] = __builtin_amdgcn_mfma_f32_16x16x32_bf16(af, bfr, acc[mt], 0, 0, 0);
            }
        }
    }

    float* ob = out + (size_t)b * K_ * C_;
    const int c = c0 + 16 * w + nl;
    #pragma unroll
    for (int mt = 0; mt < 4; ++mt)
        #pragma unroll
        for (int r = 0; r < 4; ++r)
            atomicAdd(&ob[(size_t)(mt * 16 + q * 4 + r) * C_ + c], acc[mt][r]);
}

// ---------------------------------------------------------------------------
// Row norms + global norm (fp32 exact), unchanged.
// ---------------------------------------------------------------------------
__device__ __forceinline__ float block_reduce_sum_256(float v) {
    #pragma unroll
    for (int o = 32; o > 0; o >>= 1) v += __shfl_down(v, o, 64);
    __shared__ float wsh[4];
    const int lane = threadIdx.x & 63, wid = threadIdx.x >> 6;
    if (lane == 0) wsh[wid] = v;
    __syncthreads();
    float r = 0.f;
    if (threadIdx.x == 0) r = wsh[0] + wsh[1] + wsh[2] + wsh[3];
    return r;
}

__global__ __launch_bounds__(256) void k_rnorm(
    const float* __restrict__ agg, const float* __restrict__ centroids,
    const float* __restrict__ mass, float* __restrict__ rnorm,
    float* __restrict__ gsum)
{
    const int k = blockIdx.x, b = blockIdx.y;
    const float mk = mass[b * K_ + k];
    const float* p  = agg + ((size_t)b * K_ + k) * C_;
    const float* cb = centroids + k * C_;
    float s = 0.f;
    #pragma unroll 2
    for (int i = threadIdx.x; i < C_; i += 256) {
        const float v = fmaf(-cb[i], mk, p[i]);
        s = fmaf(v, v, s);
    }
    const float ss = block_reduce_sum_256(s);
    if (threadIdx.x == 0) {
        const float rn = fmaxf(sqrtf(ss), EPSF);
        rnorm[b * K_ + k] = rn;
        atomicAdd(gsum + b, ss / (rn * rn));
    }
}

__global__ __launch_bounds__(256) void k_final(
    float* __restrict__ out, const float* __restrict__ centroids,
    const float* __restrict__ mass, const float* __restrict__ rnorm,
    const float* __restrict__ gsum)
{
    const size_t i4 = ((size_t)blockIdx.x * 256 + threadIdx.x) * 4;
    const int b = (int)(i4 >> 15);
    const int k = (int)((i4 >> 9) & 63);
    const int c = (int)(i4 & 511);
    const float gn = fmaxf(sqrtf(gsum[b]), EPSF);
    const float sc = 1.0f / (rnorm[b * K_ + k] * gn);
    const float mk = mass[b * K_ + k];
    float4 v  = *(const float4*)(out + i4);
    const float4 cv = *(const float4*)(centroids + k * C_ + c);
    v.x = fmaf(-cv.x, mk, v.x) * sc;
    v.y = fmaf(-cv.y, mk, v.y) * sc;
    v.z = fmaf(-cv.z, mk, v.z) * sc;
    v.w = fmaf(-cv.w, mk, v.w) * sc;
    *(float4*)(out + i4) = v;
}

// ---------------------------------------------------------------------------
extern "C" void kernel_launch(void* const* d_in, const int* in_sizes, int n_in,
                              void* d_out, int out_size, void* d_ws, size_t ws_size,
                              hipStream_t stream) {
    const float* x         = (const float*)d_in[0];
    const float* centroids = (const float*)d_in[1];
    const float* conv_w    = (const float*)d_in[2];
    const float* conv_b    = (const float*)d_in[3];
    // d_in[4..8] (ghost_weights, w1, b1, w2, b2): positive per-row scalars
    // cancel inside the intra-cluster L2 norm; ghost rows dropped -> unused.

    float* out = (float*)d_out;
    char*  ws  = (char*)d_ws;

    u16*   assignp = (u16*)ws;                               // 16,777,216 B
    u16*   Wp      = (u16*)(ws + 16777216);                  // 81,920 B
    float* bpad    = (float*)(ws + 16777216 + 81920);        // 320 B
    float* mass    = (float*)(ws + 16777216 + 81920 + 320);  // 8 KB
    float* rnorm   = mass + B_ * K_;
    float* gsum    = rnorm + B_ * K_;

    hipMemsetAsync(mass, 0, B_ * K_ * sizeof(float), stream);
    hipMemsetAsync(gsum, 0, B_ * sizeof(float), stream);
    hipMemsetAsync(out, 0, (size_t)out_size * sizeof(float), stream);

    k_prep<<<dim3((KP * C_ + KP + 255) / 256), 256, 0, stream>>>(conv_w, conv_b, Wp, bpad);
    k_assign<<<dim3(N_ / AN, B_), 256, 0, stream>>>(x, Wp, bpad, assignp, mass);
    k_agg<<<dim3(C_ / 64, NCH, B_), 256, 0, stream>>>(x, assignp, out);
    k_rnorm<<<dim3(K_, B_), 256, 0, stream>>>(out, centroids, mass, rnorm, gsum);
    k_final<<<(out_size / 4 + 255) / 256, 256, 0, stream>>>(out, centroids, mass, rnorm, gsum);
}

// Round 3
// 507.585 us; speedup vs baseline: 1.1262x; 1.1262x over previous
//
#include <hip/hip_runtime.h>
#include <hip/hip_bf16.h>

#define B_ 32
#define C_ 512
#define N_ 4096
#define T_ 72
#define K_ 64
#define KP 80            // clusters padded to 5 MFMA m-tiles
#define EPSF 1e-12f

typedef unsigned short u16;
typedef unsigned int u32;
typedef __attribute__((ext_vector_type(8))) short bf16x8;
typedef __attribute__((ext_vector_type(4))) float f32x4;

__device__ __forceinline__ u16 f2bf(float v) {
    __hip_bfloat16 h = __float2bfloat16(v);   // RNE
    return *reinterpret_cast<u16*>(&h);
}

// ---------------------------------------------------------------------------
// Prep: W padded [80][512] -> bf16 (rows >=72 zero); bias padded (-1e30 pads
// so padded rows vanish in softmax).
// ---------------------------------------------------------------------------
__global__ __launch_bounds__(256) void k_prep(
    const float* __restrict__ conv_w, const float* __restrict__ conv_b,
    u16* __restrict__ Wp, float* __restrict__ bp)
{
    const int idx = blockIdx.x * 256 + threadIdx.x;
    if (idx < KP * C_) {
        const int k = idx >> 9, c = idx & (C_ - 1);
        Wp[idx] = f2bf(k < T_ ? conv_w[k * C_ + c] : 0.f);
    } else if (idx < KP * C_ + KP) {
        const int j = idx - KP * C_;
        bp[j] = (j < T_) ? conv_b[j] : -1e30f;
    }
}

// ---------------------------------------------------------------------------
// Assign v3: n-window 256/block so every global load instruction is one FULL
// c-row segment of 1 KB (contiguous across the wave) -> spreads each access
// over many memory channels (the 16-KB row stride + 256-B block footprint of
// the old version camped each block on ~1 channel ~= 800 GB/s cap).
// Transpose is free in registers: wave loads 8 CONSECUTIVE c-rows per chunk;
// lane l then holds an 8c x 4n block and emits one aligned uint4 LDS write
// per n (c-contiguous fragment). 16-B c-slot rotation spreads LDS banks for
// both writes and b128 fragment reads. 2 barriers/chunk, single LDS buffer.
// LDS 21.25 KB (compiles; checked).
// ---------------------------------------------------------------------------
#define ANW 256
__global__ __launch_bounds__(256, 2) void k_assign(
    const float* __restrict__ x, const u16* __restrict__ Wp,
    const float* __restrict__ bp, u16* __restrict__ assignp,
    float* __restrict__ mass)
{
    __shared__ u16   xs[ANW * 32];   // [n 256][c-chunk 32] bf16, 16 KB
    __shared__ float red[4][ANW];    // per-wave sumsq partials
    __shared__ float inv_sh[ANW];

    const int t = threadIdx.x;
    const int b = blockIdx.y;
    const int n0 = blockIdx.x * ANW;
    const int lane = t & 63, w = t >> 6;
    const int q = lane >> 4, nl = lane & 15;

    const float* xb = x + (size_t)b * C_ * N_ + n0 + 4 * lane;

    f32x4 acc[4][5];
    #pragma unroll
    for (int nt = 0; nt < 4; ++nt)
        #pragma unroll
        for (int mt = 0; mt < 5; ++mt) acc[nt][mt] = (f32x4)0.f;
    float ss[4] = {0.f, 0.f, 0.f, 0.f};

    float4 v[8];
    bf16x8 af[5];
    // prologue: chunk 0 (wave w owns c-rows w*8 .. w*8+8 of each chunk)
    #pragma unroll
    for (int i = 0; i < 8; ++i)
        v[i] = *(const float4*)(xb + (size_t)(w * 8 + i) * N_);
    #pragma unroll
    for (int mt = 0; mt < 5; ++mt)
        af[mt] = *(const bf16x8*)(Wp + (size_t)(mt * 16 + nl) * C_ + q * 8);

#define VJ(i) (j == 0 ? v[i].x : j == 1 ? v[i].y : j == 2 ? v[i].z : v[i].w)

    #pragma unroll 1
    for (int ch = 0; ch < 16; ++ch) {
        // ---- consume registers: sumsq + c-contiguous LDS write ----
        #pragma unroll
        for (int j = 0; j < 4; ++j) {
            const float f0 = VJ(0), f1 = VJ(1), f2 = VJ(2), f3 = VJ(3);
            const float f4 = VJ(4), f5 = VJ(5), f6 = VJ(6), f7 = VJ(7);
            ss[j] = fmaf(f0, f0, ss[j]); ss[j] = fmaf(f1, f1, ss[j]);
            ss[j] = fmaf(f2, f2, ss[j]); ss[j] = fmaf(f3, f3, ss[j]);
            ss[j] = fmaf(f4, f4, ss[j]); ss[j] = fmaf(f5, f5, ss[j]);
            ss[j] = fmaf(f6, f6, ss[j]); ss[j] = fmaf(f7, f7, ss[j]);
            uint4 pk;
            pk.x = (u32)f2bf(f0) | ((u32)f2bf(f1) << 16);
            pk.y = (u32)f2bf(f2) | ((u32)f2bf(f3) << 16);
            pk.z = (u32)f2bf(f4) | ((u32)f2bf(f5) << 16);
            pk.w = (u32)f2bf(f6) | ((u32)f2bf(f7) << 16);
            const int n = 4 * lane + j;
            const int slot = (w + ((lane >> 1) & 3)) & 3;   // rotated c-slot
            *(uint4*)&xs[n * 32 + slot * 8] = pk;
        }
        __syncthreads();
        // ---- prefetch next chunk's x rows (in flight across MFMA) ----
        if (ch < 15) {
            #pragma unroll
            for (int i = 0; i < 8; ++i)
                v[i] = *(const float4*)(xb + (size_t)((ch + 1) * 32 + w * 8 + i) * N_);
        }
        __builtin_amdgcn_sched_barrier(0);
        // ---- MFMA: 4 n-tiles x 5 m-tiles, K=32 (this chunk) ----
        #pragma unroll
        for (int nt = 0; nt < 4; ++nt) {
            const int n = (4 * w + nt) * 16 + nl;
            const int slot = (q + ((n >> 3) & 3)) & 3;
            const bf16x8 bfr = *(const bf16x8*)&xs[n * 32 + slot * 8];
            #pragma unroll
            for (int mt = 0; mt < 5; ++mt)
                acc[nt][mt] = __builtin_amdgcn_mfma_f32_16x16x32_bf16(af[mt], bfr, acc[nt][mt], 0, 0, 0);
        }
        // ---- prefetch next chunk's W fragments (L2-hot) ----
        if (ch < 15) {
            #pragma unroll
            for (int mt = 0; mt < 5; ++mt)
                af[mt] = *(const bf16x8*)(Wp + (size_t)(mt * 16 + nl) * C_ + (ch + 1) * 32 + q * 8);
        }
        __syncthreads();
    }
#undef VJ

    // ---- cross-wave sumsq reduction -> inv norms ----
    *(float4*)&red[w][4 * lane] = make_float4(ss[0], ss[1], ss[2], ss[3]);
    __syncthreads();
    {
        const float s = red[0][t] + red[1][t] + red[2][t] + red[3][t];
        inv_sh[t] = 1.0f / fmaxf(sqrtf(s), EPSF);
    }
    __syncthreads();

    float bpv[5][4];
    #pragma unroll
    for (int mt = 0; mt < 5; ++mt)
        #pragma unroll
        for (int r = 0; r < 4; ++r) bpv[mt][r] = bp[mt * 16 + q * 4 + r];

    // ---- epilogue per n-tile: softmax in C-layout regs (proven math) ----
    #pragma unroll
    for (int nt = 0; nt < 4; ++nt) {
        const int n_loc = (4 * w + nt) * 16 + nl;
        const float invn = inv_sh[n_loc];
        const int nglob = n0 + n_loc;

        float lg[5][4];
        #pragma unroll
        for (int mt = 0; mt < 5; ++mt)
            #pragma unroll
            for (int r = 0; r < 4; ++r)
                lg[mt][r] = acc[nt][mt][r] * invn + bpv[mt][r];

        float mx = -1e30f;
        #pragma unroll
        for (int mt = 0; mt < 5; ++mt)
            #pragma unroll
            for (int r = 0; r < 4; ++r) mx = fmaxf(mx, lg[mt][r]);
        mx = fmaxf(mx, __shfl_xor(mx, 16, 64));
        mx = fmaxf(mx, __shfl_xor(mx, 32, 64));

        float s = 0.f;
        #pragma unroll
        for (int mt = 0; mt < 5; ++mt)
            #pragma unroll
            for (int r = 0; r < 4; ++r) {
                lg[mt][r] = __expf(lg[mt][r] - mx);
                s += lg[mt][r];
            }
        s += __shfl_xor(s, 16, 64);
        s += __shfl_xor(s, 32, 64);
        const float rs = 1.0f / s;

        #pragma unroll
        for (int mt = 0; mt < 4; ++mt)      // real clusters only
            #pragma unroll
            for (int r = 0; r < 4; ++r) {
                const float a = lg[mt][r] * rs;
                float msum = a;
                msum += __shfl_xor(msum, 1, 64);
                msum += __shfl_xor(msum, 2, 64);
                msum += __shfl_xor(msum, 4, 64);
                msum += __shfl_xor(msum, 8, 64);
                const int k = mt * 16 + q * 4 + r;
                if (nl == 0) atomicAdd(&mass[b * K_ + k], msum);
                assignp[((size_t)b * K_ + k) * N_ + nglob] = f2bf(a * invn);
            }
    }
}

// ---------------------------------------------------------------------------
// Agg (round-1 known-good): wave-independent, barrier-free. A-fragments read
// DIRECTLY from global assignp (L1/L2-hot); B (x, cvt bf16) staged into
// wave-private LDS with one-step register prefetch. NCH=8 -> 2048 blocks.
// LDS 9.2 KB/block.
// ---------------------------------------------------------------------------
#define GBK 64
#define NCH 8
__global__ __launch_bounds__(256) void k_agg(
    const float* __restrict__ x, const u16* __restrict__ assignp,
    float* __restrict__ out)
{
    __shared__ u16 Bt[4][16][72];   // per-wave 16c x 64n bf16, pitch 72

    const int t  = threadIdx.x;
    const int b  = blockIdx.z;
    const int nc0 = blockIdx.y * (N_ / NCH);
    const int c0  = blockIdx.x * 64;

    const int lane = t & 63, w = t >> 6;
    const int q = lane >> 4, nl = lane & 15;     // MFMA roles
    const int nq16 = lane & 15, cj = lane >> 4;  // staging roles

    f32x4 acc[4];
    #pragma unroll
    for (int mt = 0; mt < 4; ++mt) acc[mt] = (f32x4)0.f;

    const u16*   ab = assignp + (size_t)b * K_ * N_ + (size_t)nl * N_ + q * 8;
    const float* xb = x + ((size_t)b * C_ + c0 + 16 * w) * N_ + 4 * nq16;

    // prologue: issue first step's B loads
    float4 vb[4];
    #pragma unroll
    for (int p = 0; p < 4; ++p)
        vb[p] = *(const float4*)(xb + (size_t)(4 * p + cj) * N_ + nc0);

    #pragma unroll 1
    for (int n0 = nc0; n0 < nc0 + N_ / NCH; n0 += GBK) {
        // consume regs -> wave-private LDS (ds_write_b64)
        #pragma unroll
        for (int p = 0; p < 4; ++p) {
            const float4 v = vb[p];
            uint2 pk;
            pk.x = (u32)f2bf(v.x) | ((u32)f2bf(v.y) << 16);
            pk.y = (u32)f2bf(v.z) | ((u32)f2bf(v.w) << 16);
            *(uint2*)&Bt[w][4 * p + cj][4 * nq16] = pk;
        }
        // prefetch next step's B (in flight across the MFMA phase)
        if (n0 + GBK < nc0 + N_ / NCH) {
            #pragma unroll
            for (int p = 0; p < 4; ++p)
                vb[p] = *(const float4*)(xb + (size_t)(4 * p + cj) * N_ + n0 + GBK);
        }
        // MFMA: B from private LDS, A direct from global (L1-hot)
        #pragma unroll
        for (int kk = 0; kk < 2; ++kk) {
            const bf16x8 bfr = *(const bf16x8*)&Bt[w][nl][kk * 32 + q * 8];
            #pragma unroll
            for (int mt = 0; mt < 4; ++mt) {
                const bf16x8 af = *(const bf16x8*)(ab + (size_t)(mt * 16) * N_ + n0 + kk * 32);
                acc[mt] = __builtin_amdgcn_mfma_f32_16x16x32_bf16(af, bfr, acc[mt], 0, 0, 0);
            }
        }
    }

    float* ob = out + (size_t)b * K_ * C_;
    const int c = c0 + 16 * w + nl;
    #pragma unroll
    for (int mt = 0; mt < 4; ++mt)
        #pragma unroll
        for (int r = 0; r < 4; ++r)
            atomicAdd(&ob[(size_t)(mt * 16 + q * 4 + r) * C_ + c], acc[mt][r]);
}

// ---------------------------------------------------------------------------
// Row norms + global norm (fp32 exact), unchanged.
// ---------------------------------------------------------------------------
__device__ __forceinline__ float block_reduce_sum_256(float v) {
    #pragma unroll
    for (int o = 32; o > 0; o >>= 1) v += __shfl_down(v, o, 64);
    __shared__ float wsh[4];
    const int lane = threadIdx.x & 63, wid = threadIdx.x >> 6;
    if (lane == 0) wsh[wid] = v;
    __syncthreads();
    float r = 0.f;
    if (threadIdx.x == 0) r = wsh[0] + wsh[1] + wsh[2] + wsh[3];
    return r;
}

__global__ __launch_bounds__(256) void k_rnorm(
    const float* __restrict__ agg, const float* __restrict__ centroids,
    const float* __restrict__ mass, float* __restrict__ rnorm,
    float* __restrict__ gsum)
{
    const int k = blockIdx.x, b = blockIdx.y;
    const float mk = mass[b * K_ + k];
    const float* p  = agg + ((size_t)b * K_ + k) * C_;
    const float* cb = centroids + k * C_;
    float s = 0.f;
    #pragma unroll 2
    for (int i = threadIdx.x; i < C_; i += 256) {
        const float v = fmaf(-cb[i], mk, p[i]);
        s = fmaf(v, v, s);
    }
    const float ss = block_reduce_sum_256(s);
    if (threadIdx.x == 0) {
        const float rn = fmaxf(sqrtf(ss), EPSF);
        rnorm[b * K_ + k] = rn;
        atomicAdd(gsum + b, ss / (rn * rn));
    }
}

__global__ __launch_bounds__(256) void k_final(
    float* __restrict__ out, const float* __restrict__ centroids,
    const float* __restrict__ mass, const float* __restrict__ rnorm,
    const float* __restrict__ gsum)
{
    const size_t i4 = ((size_t)blockIdx.x * 256 + threadIdx.x) * 4;
    const int b = (int)(i4 >> 15);
    const int k = (int)((i4 >> 9) & 63);
    const int c = (int)(i4 & 511);
    const float gn = fmaxf(sqrtf(gsum[b]), EPSF);
    const float sc = 1.0f / (rnorm[b * K_ + k] * gn);
    const float mk = mass[b * K_ + k];
    float4 v  = *(const float4*)(out + i4);
    const float4 cv = *(const float4*)(centroids + k * C_ + c);
    v.x = fmaf(-cv.x, mk, v.x) * sc;
    v.y = fmaf(-cv.y, mk, v.y) * sc;
    v.z = fmaf(-cv.z, mk, v.z) * sc;
    v.w = fmaf(-cv.w, mk, v.w) * sc;
    *(float4*)(out + i4) = v;
}

// ---------------------------------------------------------------------------
extern "C" void kernel_launch(void* const* d_in, const int* in_sizes, int n_in,
                              void* d_out, int out_size, void* d_ws, size_t ws_size,
                              hipStream_t stream) {
    const float* x         = (const float*)d_in[0];
    const float* centroids = (const float*)d_in[1];
    const float* conv_w    = (const float*)d_in[2];
    const float* conv_b    = (const float*)d_in[3];
    // d_in[4..8] (ghost_weights, w1, b1, w2, b2): positive per-row scalars
    // cancel inside the intra-cluster L2 norm; ghost rows dropped -> unused.

    float* out = (float*)d_out;
    char*  ws  = (char*)d_ws;

    u16*   assignp = (u16*)ws;                               // 16,777,216 B
    u16*   Wp      = (u16*)(ws + 16777216);                  // 81,920 B
    float* bpad    = (float*)(ws + 16777216 + 81920);        // 320 B
    float* mass    = (float*)(ws + 16777216 + 81920 + 320);  // 8 KB
    float* rnorm   = mass + B_ * K_;
    float* gsum    = rnorm + B_ * K_;

    hipMemsetAsync(mass, 0, B_ * K_ * sizeof(float), stream);
    hipMemsetAsync(gsum, 0, B_ * sizeof(float), stream);
    hipMemsetAsync(out, 0, (size_t)out_size * sizeof(float), stream);

    k_prep<<<dim3((KP * C_ + KP + 255) / 256), 256, 0, stream>>>(conv_w, conv_b, Wp, bpad);
    k_assign<<<dim3(N_ / ANW, B_), 256, 0, stream>>>(x, Wp, bpad, assignp, mass);
    k_agg<<<dim3(C_ / 64, NCH, B_), 256, 0, stream>>>(x, assignp, out);
    k_rnorm<<<dim3(K_, B_), 256, 0, stream>>>(out, centroids, mass, rnorm, gsum);
    k_final<<<(out_size / 4 + 255) / 256, 256, 0, stream>>>(out, centroids, mass, rnorm, gsum);
}